// Round 5
// baseline (626.153 us; speedup 1.0000x reference)
//
#include <hip/hip_runtime.h>
#include <cstdint>
#include <cstddef>

// ---------------------------------------------------------------------------
// GCN2: h = relu(x@W0+b0); 6x { agg = scatter_sum(w*h[src] -> dst);
//        z = 0.9*agg + 0.1*x0; h = relu(z @ ((1-b)I + b*Wc)) };
//        out = h@W1 + b1
// R0 871 fp32. R1 770 (multi-block scan). R2 652 (bf16 storage, packed
// bucket). R3 592 (MFMA GEMMs, weight fold). R4: 4B edge records
// (u16 src + bf16 w -> scatter halves), fused aggregate+conv-GEMM kernel
// (gather -> z in regs -> LDS -> MFMA; h double-buffered), prepw+hist merged.
// ---------------------------------------------------------------------------

#define NN 50000
#define EE 800000

constexpr float ALPHA   = 0.1f;
constexpr float BETA_C  = 0.05406722127027574f;   // log(0.5/9 + 1)

constexpr int SCAN_B = 256;
constexpr int NB = (NN + SCAN_B - 1) / SCAN_B;    // 196 scan blocks
constexpr int HB = (EE + 255) / 256;              // 3125 hist blocks
constexpr int PREP_TOT = 128 * 128 + 6 * 128 * 128 + 64 * 128;   // 122880
constexpr int PB = (PREP_TOT + 255) / 256;        // 480 prep blocks

typedef unsigned short u16;
typedef unsigned int   u32;
typedef __attribute__((ext_vector_type(8))) short short8;   // 8 bf16 (MFMA A/B)
typedef __attribute__((ext_vector_type(4))) float f32x4;    // MFMA C/D

__device__ __forceinline__ float bf2f(u16 u) {
    union { float f; u32 i; } c; c.i = ((u32)u) << 16; return c.f;
}
__device__ __forceinline__ u16 f2bf(float f) {          // round-to-nearest-even
    union { float f; u32 i; } c; c.f = f;
    u32 r = c.i + 0x7fffu + ((c.i >> 16) & 1u);
    return (u16)(r >> 16);
}

// ------------- merged: histogram (blocks < HB) + weight prep (rest) ---------
// w0t[n][k] = bf16(W0[k][n]); wft[l][n][k] = bf16(beta*cw[l][k][n] + (k==n)*(1-beta));
// w1t[n][k] = bf16(W1[k][n])
__global__ void k_hist_prep(const int* __restrict__ edst, int* __restrict__ deg,
                            const float* __restrict__ W0, const float* __restrict__ cw,
                            const float* __restrict__ W1, u16* __restrict__ w0t,
                            u16* __restrict__ wft, u16* __restrict__ w1t, int E) {
    int b = blockIdx.x;
    if (b < HB) {
        int i = b * 256 + threadIdx.x;
        if (i < E) atomicAdd(&deg[edst[i]], 1);
    } else {
        int i = (b - HB) * 256 + threadIdx.x;
        if (i < 128 * 128) {
            int n = i >> 7, k = i & 127;
            w0t[i] = f2bf(W0[k * 128 + n]);
        } else if (i < 128 * 128 + 6 * 128 * 128) {
            int r = i - 128 * 128;
            int l = r >> 14; int t = r & 16383;
            int n = t >> 7, k = t & 127;
            float v = BETA_C * cw[l * 16384 + k * 128 + n] + ((k == n) ? (1.f - BETA_C) : 0.f);
            wft[r] = f2bf(v);
        } else if (i < PREP_TOT) {
            int r = i - (128 * 128 + 6 * 128 * 128);
            int n = r >> 7, k = r & 127;
            w1t[r] = f2bf(W1[k * 64 + n]);
        }
    }
}

// ---------------- CSR scan chain ----------------

__global__ __launch_bounds__(SCAN_B) void k_bsum(const int* __restrict__ deg,
                                                 int* __restrict__ bsum, int N) {
    int i = blockIdx.x * SCAN_B + threadIdx.x;
    int v = (i < N) ? deg[i] : 0;
#pragma unroll
    for (int o = 32; o > 0; o >>= 1) v += __shfl_down(v, o);
    __shared__ int ws[SCAN_B / 64];
    if ((threadIdx.x & 63) == 0) ws[threadIdx.x >> 6] = v;
    __syncthreads();
    if (threadIdx.x == 0) bsum[blockIdx.x] = ws[0] + ws[1] + ws[2] + ws[3];
}

__global__ __launch_bounds__(SCAN_B) void k_bscan(const int* __restrict__ bsum,
                                                  int* __restrict__ bbase, int nb) {
    __shared__ int s[SCAN_B];
    const int t = threadIdx.x;
    int v = (t < nb) ? bsum[t] : 0;
    s[t] = v;
    __syncthreads();
#pragma unroll
    for (int o = 1; o < SCAN_B; o <<= 1) {
        int u = (t >= o) ? s[t - o] : 0;
        __syncthreads();
        s[t] += u;
        __syncthreads();
    }
    if (t < nb) bbase[t] = s[t] - v;
}

__global__ __launch_bounds__(SCAN_B) void k_scan3(const int* __restrict__ deg,
                                                  const int* __restrict__ bbase,
                                                  int* __restrict__ offs,
                                                  int* __restrict__ cursor, int N) {
    __shared__ int s[SCAN_B];
    const int t = threadIdx.x;
    const int i = blockIdx.x * SCAN_B + t;
    int v = (i < N) ? deg[i] : 0;
    s[t] = v;
    __syncthreads();
#pragma unroll
    for (int o = 1; o < SCAN_B; o <<= 1) {
        int u = (t >= o) ? s[t - o] : 0;
        __syncthreads();
        s[t] += u;
        __syncthreads();
    }
    int ex = bbase[blockIdx.x] + s[t] - v;
    if (i < N) {
        offs[i]   = ex;
        cursor[i] = ex;
        if (i == N - 1) offs[N] = ex + v;
    }
}

// pack (src u16, weight bf16) -> single 4B store per edge
__global__ void k_bucket(const int* __restrict__ src, const int* __restrict__ dst,
                         const float* __restrict__ w, int* __restrict__ cursor,
                         u32* __restrict__ ep, int E) {
    int i = blockIdx.x * blockDim.x + threadIdx.x;
    if (i < E) {
        int d = dst[i];
        int p = atomicAdd(&cursor[d], 1);
        ep[p] = ((u32)f2bf(w[i]) << 16) | (u32)src[i];
    }
}

// ---------------- fused conv: gather + z + MFMA GEMM ----------------
// One wave = 16 nodes. Per node: 64 lanes gather-accumulate (lane owns feats
// {2l,2l+1}), z = 0.9*agg + 0.1*x0 in regs, bf16 z row -> LDS. Then the wave
// computes h[node] = relu(z @ Wfold) via 8 col-tiles x 4 k-step MFMAs reading
// B-fragments from LDS. hin/hout MUST be distinct buffers (gather reads other
// nodes' rows while we write).
__global__ __launch_bounds__(256) void k_conv(const int* __restrict__ offs,
                                              const u32* __restrict__ ep,
                                              const u16* __restrict__ hin,
                                              const u16* __restrict__ x0,
                                              const u16* __restrict__ Wt,
                                              u16* __restrict__ hout, int N) {
    __shared__ __align__(16) u16 zl[4][16][136];   // per-wave z rows, +8 pad
    const int lane = threadIdx.x & 63;
    const int wave = threadIdx.x >> 6;
    const int base = blockIdx.x * 64 + wave * 16;

    for (int nn = 0; nn < 16; ++nn) {
        const int n = base + nn;
        const int nc = n < N ? n : N - 1;
        const int beg = offs[nc], end = offs[nc + 1];
        float ax = 0.f, ay = 0.f;
        int e = beg;
        for (; e + 15 < end; e += 16) {
            u32 r[16], v[16];
#pragma unroll
            for (int j = 0; j < 16; ++j) r[j] = ep[e + j];
#pragma unroll
            for (int j = 0; j < 16; ++j)
                v[j] = ((const u32*)(hin + (size_t)(r[j] & 0xffffu) * 128))[lane];
#pragma unroll
            for (int j = 0; j < 16; ++j) {
                float w = bf2f((u16)(r[j] >> 16));
                ax += w * bf2f((u16)v[j]);
                ay += w * bf2f((u16)(v[j] >> 16));
            }
        }
        for (; e + 3 < end; e += 4) {
            u32 r[4], v[4];
#pragma unroll
            for (int j = 0; j < 4; ++j) r[j] = ep[e + j];
#pragma unroll
            for (int j = 0; j < 4; ++j)
                v[j] = ((const u32*)(hin + (size_t)(r[j] & 0xffffu) * 128))[lane];
#pragma unroll
            for (int j = 0; j < 4; ++j) {
                float w = bf2f((u16)(r[j] >> 16));
                ax += w * bf2f((u16)v[j]);
                ay += w * bf2f((u16)(v[j] >> 16));
            }
        }
        for (; e < end; ++e) {
            u32 r = ep[e];
            u32 v = ((const u32*)(hin + (size_t)(r & 0xffffu) * 128))[lane];
            float w = bf2f((u16)(r >> 16));
            ax += w * bf2f((u16)v);
            ay += w * bf2f((u16)(v >> 16));
        }
        // z = (1-alpha)*agg + alpha*x0  (one less bf16 rounding than R3)
        u32 xv = ((const u32*)(x0 + (size_t)nc * 128))[lane];
        float zx = (1.f - ALPHA) * ax + ALPHA * bf2f((u16)xv);
        float zy = (1.f - ALPHA) * ay + ALPHA * bf2f((u16)(xv >> 16));
        ((u32*)&zl[wave][nn][0])[lane] = (u32)f2bf(zx) | ((u32)f2bf(zy) << 16);
    }
    __syncthreads();

    // ---- MFMA phase (layout identical to R3's verified GEMM)
    const int q = lane >> 4;          // quad
    const int m16 = lane & 15;        // node within tile / output-feature row
    short8 zf[4];
#pragma unroll
    for (int s = 0; s < 4; ++s)
        zf[s] = *(const short8*)&zl[wave][m16][s * 32 + q * 8];

    f32x4 acc[8];
#pragma unroll
    for (int c = 0; c < 8; ++c) {
        f32x4 a = {0.f, 0.f, 0.f, 0.f};
        const u16* wp = Wt + (size_t)(c * 16 + m16) * 128 + q * 8;
#pragma unroll
        for (int s = 0; s < 4; ++s) {
            short8 wf = *(const short8*)(wp + s * 32);
            a = __builtin_amdgcn_mfma_f32_16x16x32_bf16(wf, zf[s], a, 0, 0, 0);
        }
        acc[c] = a;
    }

    const int node = base + m16;
    if (node < N) {
#pragma unroll
        for (int c = 0; c < 8; ++c) {
            float v0 = acc[c][0] > 0.f ? acc[c][0] : 0.f;
            float v1 = acc[c][1] > 0.f ? acc[c][1] : 0.f;
            float v2 = acc[c][2] > 0.f ? acc[c][2] : 0.f;
            float v3 = acc[c][3] > 0.f ? acc[c][3] : 0.f;
            ushort4 o;
            o.x = f2bf(v0); o.y = f2bf(v1); o.z = f2bf(v2); o.w = f2bf(v3);
            *(ushort4*)(hout + (size_t)node * 128 + c * 16 + q * 4) = o;
        }
    }
}

// ---------------- standalone MFMA GEMM (first & last layer) ----------------
// MODE 0: Av = x fp32 [M,128]; C = relu(x@W + bias) -> bf16
// MODE 2: Av = h bf16 [M,128]; C = h@W + bias -> fp32 [M,64]
template <int NT, int MODE>
__global__ __launch_bounds__(256) void k_gemm_mfma(const void* __restrict__ Av,
                                                   const u16* __restrict__ Wt,
                                                   const float* __restrict__ bias,
                                                   void* __restrict__ Cv, int M) {
    const int lane = threadIdx.x & 63;
    const int wave = threadIdx.x >> 6;
    const int q = lane >> 4;
    const int m16 = lane & 15;
    const int node = blockIdx.x * 64 + wave * 16 + m16;
    const int nload = node < M ? node : M - 1;

    short8 zf[4];
    if (MODE == 0) {
        const float* xp = (const float*)Av + (size_t)nload * 128 + q * 8;
#pragma unroll
        for (int s = 0; s < 4; ++s) {
            float4 u0 = *(const float4*)(xp + s * 32);
            float4 u1 = *(const float4*)(xp + s * 32 + 4);
            short8 z;
            z[0] = (short)f2bf(u0.x); z[1] = (short)f2bf(u0.y);
            z[2] = (short)f2bf(u0.z); z[3] = (short)f2bf(u0.w);
            z[4] = (short)f2bf(u1.x); z[5] = (short)f2bf(u1.y);
            z[6] = (short)f2bf(u1.z); z[7] = (short)f2bf(u1.w);
            zf[s] = z;
        }
    } else {
        const u16* ap = (const u16*)Av + (size_t)nload * 128 + q * 8;
#pragma unroll
        for (int s = 0; s < 4; ++s)
            zf[s] = *(const short8*)(ap + s * 32);
    }

    f32x4 acc[NT];
#pragma unroll
    for (int c = 0; c < NT; ++c) {
        f32x4 a = {0.f, 0.f, 0.f, 0.f};
        const u16* wp = Wt + (size_t)(c * 16 + m16) * 128 + q * 8;
#pragma unroll
        for (int s = 0; s < 4; ++s) {
            short8 wf = *(const short8*)(wp + s * 32);
            a = __builtin_amdgcn_mfma_f32_16x16x32_bf16(wf, zf[s], a, 0, 0, 0);
        }
        acc[c] = a;
    }

    if (node < M) {
#pragma unroll
        for (int c = 0; c < NT; ++c) {
            const int n0 = c * 16 + q * 4;
            float4 bv = *(const float4*)(bias + n0);
            if (MODE == 2) {
                float4 o;
                o.x = acc[c][0] + bv.x; o.y = acc[c][1] + bv.y;
                o.z = acc[c][2] + bv.z; o.w = acc[c][3] + bv.w;
                *(float4*)((float*)Cv + (size_t)node * (NT * 16) + n0) = o;
            } else {
                float v0 = acc[c][0] + bv.x; v0 = v0 > 0.f ? v0 : 0.f;
                float v1 = acc[c][1] + bv.y; v1 = v1 > 0.f ? v1 : 0.f;
                float v2 = acc[c][2] + bv.z; v2 = v2 > 0.f ? v2 : 0.f;
                float v3 = acc[c][3] + bv.w; v3 = v3 > 0.f ? v3 : 0.f;
                ushort4 o;
                o.x = f2bf(v0); o.y = f2bf(v1); o.z = f2bf(v2); o.w = f2bf(v3);
                *(ushort4*)((u16*)Cv + (size_t)node * 128 + n0) = o;
            }
        }
    }
}

// ---------------------------------------------------------------------------

extern "C" void kernel_launch(void* const* d_in, const int* in_sizes, int n_in,
                              void* d_out, int out_size, void* d_ws, size_t ws_size,
                              hipStream_t stream) {
    const float* x    = (const float*)d_in[0];
    const int*   esrc = (const int*)d_in[1];
    const int*   edst = (const int*)d_in[2];
    const float* ew   = (const float*)d_in[3];
    const float* W0   = (const float*)d_in[4];
    const float* b0   = (const float*)d_in[5];
    const float* W1   = (const float*)d_in[6];
    const float* b1   = (const float*)d_in[7];
    const float* cw   = (const float*)d_in[8];
    float* out = (float*)d_out;

    const int N = NN, E = EE;

    // workspace layout (all rewritten every call)
    u32*  ep4   = (u32*)d_ws;                       // E      4B edge records
    u16*  x0b   = (u16*)(ep4 + E);                  // [N,128] bf16 x0
    u16*  hb1   = x0b + (size_t)N * 128;            // [N,128] bf16 h (ping)
    u16*  hb2   = hb1 + (size_t)N * 128;            // [N,128] bf16 h (pong)
    u16*  w0t   = hb2 + (size_t)N * 128;            // 128*128
    u16*  wft   = w0t + 128 * 128;                  // 6*128*128
    u16*  w1t   = wft + 6 * 128 * 128;              // 64*128
    int*  deg   = (int*)(w1t + 64 * 128);
    int*  offs  = deg  + N;                         // N+1
    int*  cur   = offs + N + 1;                     // N
    int*  bsum  = cur  + N;                         // NB
    int*  bbase = bsum + NB;                        // NB

    // ---- CSR build + weight prep
    hipMemsetAsync(deg, 0, (size_t)N * sizeof(int), stream);
    k_hist_prep<<<HB + PB, 256, 0, stream>>>(edst, deg, W0, cw, W1, w0t, wft, w1t, E);
    k_bsum<<<NB, SCAN_B, 0, stream>>>(deg, bsum, N);
    k_bscan<<<1, SCAN_B, 0, stream>>>(bsum, bbase, NB);
    k_scan3<<<NB, SCAN_B, 0, stream>>>(deg, bbase, offs, cur, N);
    k_bucket<<<(E + 255) / 256, 256, 0, stream>>>(esrc, edst, ew, cur, ep4, E);

    const int gx = (N + 63) / 64;   // 782 blocks, 4 waves each, 16 nodes/wave

    // ---- layer 0: x0 = relu(x@W0 + b0)
    k_gemm_mfma<8, 0><<<gx, 256, 0, stream>>>(x, w0t, b0, x0b, N);

    // ---- 6 fused GCN2 convs (h double-buffered: in != out)
    const u16* hin = x0b;
    u16* houts[6] = {hb1, hb2, hb1, hb2, hb1, hb2};
    for (int i = 0; i < 6; ++i) {
        k_conv<<<gx, 256, 0, stream>>>(offs, ep4, hin, x0b,
                                       wft + (size_t)i * 16384, houts[i], N);
        hin = houts[i];
    }

    // ---- final: out = h@W1 + b1
    k_gemm_mfma<4, 2><<<gx, 256, 0, stream>>>(hb2, w1t, b1, out, N);
}

// Round 6
// 602.662 us; speedup vs baseline: 1.0390x; 1.0390x over previous
//
#include <hip/hip_runtime.h>
#include <cstdint>
#include <cstddef>

// ---------------------------------------------------------------------------
// GCN2: h = relu(x@W0+b0); 6x { agg = scatter_sum(w*h[src] -> dst);
//        z = 0.9*agg + 0.1*x0; h = relu(z @ ((1-b)I + b*Wc)) };
//        out = h@W1 + b1
// R0 871 fp32. R1 770 scan fix. R2 652 bf16+packed bucket. R3 592 MFMA+fold.
// R4 626 REGRESSION: fused agg+GEMM starved the gather of waves (782 blocks,
// 27% occupancy) and h-table (12.8MB) thrashed 4MB/XCD L2 (FETCH 81MB/conv).
// R5: un-fuse; node features in slab layout [4][N][32] so each gather slab is
// 3.2MB (L2-resident); aggregate grid (3125,4) = 50000 waves, 4 nodes/wave x
// 16 lanes; z-fold in aggregate epilogue; slab==MFMA k-step so GEMM reads
// fragments natively. Keep 4B edge records (u16 src | bf16 w).
// ---------------------------------------------------------------------------

#define NN 50000
#define EE 800000

constexpr float ALPHA   = 0.1f;
constexpr float BETA_C  = 0.05406722127027574f;   // log(0.5/9 + 1)

constexpr int SCAN_B = 256;
constexpr int NB = (NN + SCAN_B - 1) / SCAN_B;    // 196 scan blocks
constexpr int HB = (EE + 255) / 256;              // 3125 hist blocks
constexpr int PREP_TOT = 128 * 128 + 6 * 128 * 128 + 64 * 128;   // 122880
constexpr int PB = (PREP_TOT + 255) / 256;        // 480 prep blocks

typedef unsigned short u16;
typedef unsigned int   u32;
typedef __attribute__((ext_vector_type(8))) short short8;   // 8 bf16 (MFMA A/B)
typedef __attribute__((ext_vector_type(4))) float f32x4;    // MFMA C/D

__device__ __forceinline__ float bf2f(u16 u) {
    union { float f; u32 i; } c; c.i = ((u32)u) << 16; return c.f;
}
__device__ __forceinline__ u16 f2bf(float f) {          // round-to-nearest-even
    union { float f; u32 i; } c; c.f = f;
    u32 r = c.i + 0x7fffu + ((c.i >> 16) & 1u);
    return (u16)(r >> 16);
}

// ------------- merged: histogram (blocks < HB) + weight prep (rest) ---------
__global__ void k_hist_prep(const int* __restrict__ edst, int* __restrict__ deg,
                            const float* __restrict__ W0, const float* __restrict__ cw,
                            const float* __restrict__ W1, u16* __restrict__ w0t,
                            u16* __restrict__ wft, u16* __restrict__ w1t, int E) {
    int b = blockIdx.x;
    if (b < HB) {
        int i = b * 256 + threadIdx.x;
        if (i < E) atomicAdd(&deg[edst[i]], 1);
    } else {
        int i = (b - HB) * 256 + threadIdx.x;
        if (i < 128 * 128) {
            int n = i >> 7, k = i & 127;
            w0t[i] = f2bf(W0[k * 128 + n]);
        } else if (i < 128 * 128 + 6 * 128 * 128) {
            int r = i - 128 * 128;
            int l = r >> 14; int t = r & 16383;
            int n = t >> 7, k = t & 127;
            float v = BETA_C * cw[l * 16384 + k * 128 + n] + ((k == n) ? (1.f - BETA_C) : 0.f);
            wft[r] = f2bf(v);
        } else if (i < PREP_TOT) {
            int r = i - (128 * 128 + 6 * 128 * 128);
            int n = r >> 7, k = r & 127;
            w1t[r] = f2bf(W1[k * 64 + n]);
        }
    }
}

// ---------------- CSR scan chain ----------------

__global__ __launch_bounds__(SCAN_B) void k_bsum(const int* __restrict__ deg,
                                                 int* __restrict__ bsum, int N) {
    int i = blockIdx.x * SCAN_B + threadIdx.x;
    int v = (i < N) ? deg[i] : 0;
#pragma unroll
    for (int o = 32; o > 0; o >>= 1) v += __shfl_down(v, o);
    __shared__ int ws[SCAN_B / 64];
    if ((threadIdx.x & 63) == 0) ws[threadIdx.x >> 6] = v;
    __syncthreads();
    if (threadIdx.x == 0) bsum[blockIdx.x] = ws[0] + ws[1] + ws[2] + ws[3];
}

__global__ __launch_bounds__(SCAN_B) void k_bscan(const int* __restrict__ bsum,
                                                  int* __restrict__ bbase, int nb) {
    __shared__ int s[SCAN_B];
    const int t = threadIdx.x;
    int v = (t < nb) ? bsum[t] : 0;
    s[t] = v;
    __syncthreads();
#pragma unroll
    for (int o = 1; o < SCAN_B; o <<= 1) {
        int u = (t >= o) ? s[t - o] : 0;
        __syncthreads();
        s[t] += u;
        __syncthreads();
    }
    if (t < nb) bbase[t] = s[t] - v;
}

__global__ __launch_bounds__(SCAN_B) void k_scan3(const int* __restrict__ deg,
                                                  const int* __restrict__ bbase,
                                                  int* __restrict__ offs,
                                                  int* __restrict__ cursor, int N) {
    __shared__ int s[SCAN_B];
    const int t = threadIdx.x;
    const int i = blockIdx.x * SCAN_B + t;
    int v = (i < N) ? deg[i] : 0;
    s[t] = v;
    __syncthreads();
#pragma unroll
    for (int o = 1; o < SCAN_B; o <<= 1) {
        int u = (t >= o) ? s[t - o] : 0;
        __syncthreads();
        s[t] += u;
        __syncthreads();
    }
    int ex = bbase[blockIdx.x] + s[t] - v;
    if (i < N) {
        offs[i]   = ex;
        cursor[i] = ex;
        if (i == N - 1) offs[N] = ex + v;
    }
}

// pack (src u16, weight bf16) -> single 4B store per edge
__global__ void k_bucket(const int* __restrict__ src, const int* __restrict__ dst,
                         const float* __restrict__ w, int* __restrict__ cursor,
                         u32* __restrict__ ep, int E) {
    int i = blockIdx.x * blockDim.x + threadIdx.x;
    if (i < E) {
        int d = dst[i];
        int p = atomicAdd(&cursor[d], 1);
        ep[p] = ((u32)f2bf(w[i]) << 16) | (u32)src[i];
    }
}

// ---------------- slab-tiled aggregate + z-fold ----------------
// Node features live in slab layout: F[s][n][32] bf16 (s = 0..3 = MFMA k-step).
// One slab = 3.2 MB -> L2-resident. Grid (N/16, 4): blockIdx.y = slab,
// wave = 4 nodes x 16 lanes, lane owns features {2f, 2f+1} of slab s.
// Epilogue: z = (1-alpha)*agg + alpha*x0, written bf16 to zs (same layout).
__global__ __launch_bounds__(256) void k_agg_z(const int* __restrict__ offs,
                                               const u32* __restrict__ ep,
                                               const u16* __restrict__ hs,
                                               const u16* __restrict__ x0s,
                                               u16* __restrict__ zs) {
    const int lane = threadIdx.x & 63;
    const int wave = threadIdx.x >> 6;
    const int g  = lane >> 4;          // node group 0..3
    const int fl = lane & 15;          // u32 index within 32-feat row
    const int s  = blockIdx.y;
    const int n  = blockIdx.x * 16 + wave * 4 + g;       // N = 3125*16 exact
    const u32* table = (const u32*)hs + (size_t)s * NN * 16;

    const int beg = offs[n], end = offs[n + 1];
    float ax = 0.f, ay = 0.f;
    int e = beg;
    for (; e + 7 < end; e += 8) {
        u32 r[8], v[8];
#pragma unroll
        for (int j = 0; j < 8; ++j) r[j] = ep[e + j];
#pragma unroll
        for (int j = 0; j < 8; ++j)
            v[j] = table[(size_t)(r[j] & 0xffffu) * 16 + fl];
#pragma unroll
        for (int j = 0; j < 8; ++j) {
            float w = bf2f((u16)(r[j] >> 16));
            ax += w * bf2f((u16)v[j]);
            ay += w * bf2f((u16)(v[j] >> 16));
        }
    }
    for (; e < end; ++e) {
        u32 r = ep[e];
        u32 v = table[(size_t)(r & 0xffffu) * 16 + fl];
        float w = bf2f((u16)(r >> 16));
        ax += w * bf2f((u16)v);
        ay += w * bf2f((u16)(v >> 16));
    }
    const size_t idx = (size_t)s * NN * 16 + (size_t)n * 16 + fl;
    u32 xv = ((const u32*)x0s)[idx];
    float zx = (1.f - ALPHA) * ax + ALPHA * bf2f((u16)xv);
    float zy = (1.f - ALPHA) * ay + ALPHA * bf2f((u16)(xv >> 16));
    ((u32*)zs)[idx] = (u32)f2bf(zx) | ((u32)f2bf(zy) << 16);
}

// ---------------- MFMA GEMM (slab-layout node features) ----------------
// MODE 0: Av = x fp32 row-major [M,128]; C = relu(x@W + bias) -> bf16 slab
// MODE 1: Av = z bf16 slab; C = relu(z @ Wfold) -> bf16 slab (no bias)
// MODE 2: Av = h bf16 slab; C = h@W1 + bias -> fp32 row-major [M,64]
template <int MODE>
__global__ __launch_bounds__(256) void k_gemm_mfma(const void* __restrict__ Av,
                                                   const u16* __restrict__ Wt,
                                                   const float* __restrict__ bias,
                                                   void* __restrict__ Cv, int M) {
    constexpr int NT = (MODE == 2) ? 4 : 8;
    const int lane = threadIdx.x & 63;
    const int wave = threadIdx.x >> 6;
    const int q = lane >> 4;
    const int m16 = lane & 15;
    const int node = blockIdx.x * 64 + wave * 16 + m16;
    const int nload = node < M ? node : M - 1;

    short8 zf[4];
    if (MODE == 0) {
        const float* xp = (const float*)Av + (size_t)nload * 128 + q * 8;
#pragma unroll
        for (int s = 0; s < 4; ++s) {
            float4 u0 = *(const float4*)(xp + s * 32);
            float4 u1 = *(const float4*)(xp + s * 32 + 4);
            short8 z;
            z[0] = (short)f2bf(u0.x); z[1] = (short)f2bf(u0.y);
            z[2] = (short)f2bf(u0.z); z[3] = (short)f2bf(u0.w);
            z[4] = (short)f2bf(u1.x); z[5] = (short)f2bf(u1.y);
            z[6] = (short)f2bf(u1.z); z[7] = (short)f2bf(u1.w);
            zf[s] = z;
        }
    } else {
        const u16* ap = (const u16*)Av;
#pragma unroll
        for (int s = 0; s < 4; ++s)
            zf[s] = *(const short8*)(ap + (size_t)s * NN * 32 + (size_t)nload * 32 + q * 8);
    }

    f32x4 acc[NT];
#pragma unroll
    for (int c = 0; c < NT; ++c) {
        f32x4 a = {0.f, 0.f, 0.f, 0.f};
        const u16* wp = Wt + (size_t)(c * 16 + m16) * 128 + q * 8;
#pragma unroll
        for (int s = 0; s < 4; ++s) {
            short8 wf = *(const short8*)(wp + s * 32);
            a = __builtin_amdgcn_mfma_f32_16x16x32_bf16(wf, zf[s], a, 0, 0, 0);
        }
        acc[c] = a;
    }

    if (node < M) {
#pragma unroll
        for (int c = 0; c < NT; ++c) {
            const int f0 = c * 16 + q * 4;     // output feature base
            if (MODE == 2) {
                float4 bv = *(const float4*)(bias + f0);
                float4 o;
                o.x = acc[c][0] + bv.x; o.y = acc[c][1] + bv.y;
                o.z = acc[c][2] + bv.z; o.w = acc[c][3] + bv.w;
                *(float4*)((float*)Cv + (size_t)node * 64 + f0) = o;
            } else {
                float v0 = acc[c][0], v1 = acc[c][1], v2 = acc[c][2], v3 = acc[c][3];
                if (MODE == 0) {
                    float4 bv = *(const float4*)(bias + f0);
                    v0 += bv.x; v1 += bv.y; v2 += bv.z; v3 += bv.w;
                }
                v0 = v0 > 0.f ? v0 : 0.f;
                v1 = v1 > 0.f ? v1 : 0.f;
                v2 = v2 > 0.f ? v2 : 0.f;
                v3 = v3 > 0.f ? v3 : 0.f;
                ushort4 o;
                o.x = f2bf(v0); o.y = f2bf(v1); o.z = f2bf(v2); o.w = f2bf(v3);
                // slab store: slab = f0>>5, offset = f0&31
                *(ushort4*)((u16*)Cv + (size_t)(f0 >> 5) * NN * 32
                            + (size_t)node * 32 + (f0 & 31)) = o;
            }
        }
    }
}

// ---------------------------------------------------------------------------

extern "C" void kernel_launch(void* const* d_in, const int* in_sizes, int n_in,
                              void* d_out, int out_size, void* d_ws, size_t ws_size,
                              hipStream_t stream) {
    const float* x    = (const float*)d_in[0];
    const int*   esrc = (const int*)d_in[1];
    const int*   edst = (const int*)d_in[2];
    const float* ew   = (const float*)d_in[3];
    const float* W0   = (const float*)d_in[4];
    const float* b0   = (const float*)d_in[5];
    const float* W1   = (const float*)d_in[6];
    const float* b1   = (const float*)d_in[7];
    const float* cw   = (const float*)d_in[8];
    float* out = (float*)d_out;

    const int N = NN, E = EE;

    // workspace layout (all rewritten every call); slab buffers are [4][N][32]
    u32*  ep4   = (u32*)d_ws;                       // E     4B edge records
    u16*  x0s   = (u16*)(ep4 + E);                  // 4*N*32 bf16 x0 (slab)
    u16*  hb1   = x0s + (size_t)4 * N * 32;         // 4*N*32 bf16 h ping
    u16*  hb2   = hb1 + (size_t)4 * N * 32;         // 4*N*32 bf16 h pong
    u16*  zsb   = hb2 + (size_t)4 * N * 32;         // 4*N*32 bf16 z
    u16*  w0t   = zsb + (size_t)4 * N * 32;         // 128*128
    u16*  wft   = w0t + 128 * 128;                  // 6*128*128
    u16*  w1t   = wft + 6 * 128 * 128;              // 64*128
    int*  deg   = (int*)(w1t + 64 * 128);
    int*  offs  = deg  + N;                         // N+1
    int*  cur   = offs + N + 1;                     // N
    int*  bsum  = cur  + N;                         // NB
    int*  bbase = bsum + NB;                        // NB

    // ---- CSR build + weight prep
    hipMemsetAsync(deg, 0, (size_t)N * sizeof(int), stream);
    k_hist_prep<<<HB + PB, 256, 0, stream>>>(edst, deg, W0, cw, W1, w0t, wft, w1t, E);
    k_bsum<<<NB, SCAN_B, 0, stream>>>(deg, bsum, N);
    k_bscan<<<1, SCAN_B, 0, stream>>>(bsum, bbase, NB);
    k_scan3<<<NB, SCAN_B, 0, stream>>>(deg, bbase, offs, cur, N);
    k_bucket<<<(E + 255) / 256, 256, 0, stream>>>(esrc, edst, ew, cur, ep4, E);

    const int gx = (N + 63) / 64;          // 782 GEMM blocks
    const dim3 ga(N / 16, 4);              // 3125 x 4 aggregate blocks

    // ---- layer 0: x0 = relu(x@W0 + b0)  (fp32 row-major -> bf16 slab)
    k_gemm_mfma<0><<<gx, 256, 0, stream>>>(x, w0t, b0, x0s, N);

    // ---- 6 GCN2 convs: z = 0.9*agg(h) + 0.1*x0 ; h' = relu(z @ Wfold)
    const u16* hin = x0s;
    u16* houts[6] = {hb1, hb2, hb1, hb2, hb1, hb2};
    for (int i = 0; i < 6; ++i) {
        k_agg_z<<<ga, 256, 0, stream>>>(offs, ep4, hin, x0s, zsb);
        k_gemm_mfma<1><<<gx, 256, 0, stream>>>(zsb, wft + (size_t)i * 16384,
                                               nullptr, houts[i], N);
        hin = houts[i];
    }

    // ---- final: out = h@W1 + b1  (bf16 slab -> fp32 row-major)
    k_gemm_mfma<2><<<gx, 256, 0, stream>>>(hb2, w1t, b1, out, N);
}

// Round 8
// 552.370 us; speedup vs baseline: 1.1336x; 1.0910x over previous
//
#include <hip/hip_runtime.h>
#include <cstdint>
#include <cstddef>

// ---------------------------------------------------------------------------
// GCN2: h = relu(x@W0+b0); 6x { agg = scatter_sum(w*h[src] -> dst);
//        z = 0.9*agg + 0.1*x0; h = relu(z @ ((1-b)I + b*Wc)) };
//        out = h@W1 + b1
// R0 871 fp32. R1 770 scan fix. R2 652 bf16+packed bucket. R3 592 MFMA+fold.
// R4 626 fused-conv regression (occupancy). R5/R6 602 slab layout.
// R7 FAILED: hipLaunchCooperativeKernel errors in this harness — never again.
// R8 (this): back to R6 multi-dispatch +
//   (a) 8-way dst-sliced bucket scatter: writes to ep4 stay within one
//       ~400KB slice region per block-group -> L2 write merge (R6 showed
//       WRITE is line-bound at E*64B regardless of record size);
//   (b) aggregate lanes own uint2 (4 feats): 8 nodes/gather-instr, 2x MLP;
//   (c) publish-first parallel-lookback scan: 3 dispatches -> 1.
// ---------------------------------------------------------------------------

#define NN 50000
#define EE 800000

constexpr float ALPHA   = 0.1f;
constexpr float BETA_C  = 0.05406722127027574f;   // log(0.5/9 + 1)

constexpr int NB = (NN + 255) / 256;              // 196 scan blocks
constexpr int HB = (EE + 255) / 256;              // 3125 edge chunks
constexpr int PREP_TOT = 128 * 128 + 6 * 128 * 128 + 64 * 128;   // 122880
constexpr int PB = (PREP_TOT + 255) / 256;        // 480 prep blocks
constexpr int SLICE = NN / 8;                     // 6250 dst nodes per slice
constexpr int NCH = (NN + 31) / 32;               // 1563 agg chunks (32 nodes)

typedef unsigned short u16;
typedef unsigned int   u32;
typedef __attribute__((ext_vector_type(8))) short short8;   // 8 bf16 (MFMA A/B)
typedef __attribute__((ext_vector_type(4))) float f32x4;    // MFMA C/D

__device__ __forceinline__ float bf2f(u16 u) {
    union { float f; u32 i; } c; c.i = ((u32)u) << 16; return c.f;
}
__device__ __forceinline__ u16 f2bf(float f) {          // round-to-nearest-even
    union { float f; u32 i; } c; c.f = f;
    u32 r = c.i + 0x7fffu + ((c.i >> 16) & 1u);
    return (u16)(r >> 16);
}

// ------------- merged: histogram (blocks < HB) + weight prep (rest) ---------
__global__ void k_hist_prep(const int* __restrict__ edst, int* __restrict__ deg,
                            const float* __restrict__ W0, const float* __restrict__ cw,
                            const float* __restrict__ W1, u16* __restrict__ w0t,
                            u16* __restrict__ wft, u16* __restrict__ w1t, int E) {
    int b = blockIdx.x;
    if (b < HB) {
        int i = b * 256 + threadIdx.x;
        if (i < E) atomicAdd(&deg[edst[i]], 1);
    } else {
        int i = (b - HB) * 256 + threadIdx.x;
        if (i < 16384) {
            int n = i >> 7, k = i & 127;
            w0t[i] = f2bf(W0[k * 128 + n]);
        } else if (i < 16384 + 6 * 16384) {
            int r = i - 16384;
            int l = r >> 14; int t = r & 16383;
            int n = t >> 7, k = t & 127;
            float v = BETA_C * cw[l * 16384 + k * 128 + n]
                      + ((k == n) ? (1.f - BETA_C) : 0.f);
            wft[r] = f2bf(v);
        } else if (i < PREP_TOT) {
            int r = i - (16384 + 6 * 16384);
            int n = r >> 7, k = r & 127;
            w1t[r] = f2bf(W1[k * 64 + n]);
        }
    }
}

// ---------------- single-dispatch scan: publish-first parallel lookback -----
// bsum[] pre-zeroed by host memset. Every block publishes local_total+1
// FIRST (nonzero = flag), then spins reading predecessors in parallel.
// 196 blocks are trivially co-resident on 256 CUs -> no deadlock window.
__global__ __launch_bounds__(256) void k_scan_lb(const int* __restrict__ deg,
                                                 int* __restrict__ bsum,
                                                 int* __restrict__ offs,
                                                 int* __restrict__ cur) {
    __shared__ int sh[256];
    __shared__ int sw[4];
    const int c = blockIdx.x, tid = threadIdx.x;
    const int i = c * 256 + tid;
    int v = (i < NN) ? deg[i] : 0;
    sh[tid] = v;
    __syncthreads();
#pragma unroll
    for (int o = 1; o < 256; o <<= 1) {
        int u = (tid >= o) ? sh[tid - o] : 0;
        __syncthreads();
        sh[tid] += u;
        __syncthreads();
    }
    if (tid == 255) atomicExch(&bsum[c], sh[255] + 1);   // publish (nonzero)
    int part = 0;
    for (int t = tid; t < c; t += 256) {                 // parallel lookback
        int b;
        do { b = atomicAdd(&bsum[t], 0); } while (b == 0);
        part += b - 1;
    }
#pragma unroll
    for (int o = 32; o > 0; o >>= 1) part += __shfl_down(part, o);
    if ((tid & 63) == 0) sw[tid >> 6] = part;
    __syncthreads();
    const int base = sw[0] + sw[1] + sw[2] + sw[3];
    const int ex = base + sh[tid] - v;
    if (i < NN) {
        offs[i] = ex;
        cur[i]  = ex;
        if (i == NN - 1) offs[NN] = ex + v;
    }
}

// ---------------- 8-way dst-sliced bucket scatter ----------------
// Block b: slice = b&7 (dst in [slice*6250, +6250)), chunk = b>>3.
// All writes from one slice-group land in a contiguous ~400KB ep4 region ->
// lines merge in (one XCD's) L2 instead of ping-ponging across 8 XCDs.
__global__ void k_bucket_x(const int* __restrict__ src, const int* __restrict__ dst,
                           const float* __restrict__ w, int* __restrict__ cur,
                           u32* __restrict__ ep, int E) {
    const int slice = blockIdx.x & 7;
    const int i = (blockIdx.x >> 3) * 256 + threadIdx.x;
    if (i >= E) return;
    const int d = dst[i];
    const int lo = slice * SLICE;
    if (d >= lo && d < lo + SLICE) {
        int pos = atomicAdd(&cur[d], 1);
        ep[pos] = ((u32)f2bf(w[i]) << 16) | (u32)src[i];
    }
}

// ---------------- slab-tiled aggregate + z-fold (uint2 lanes) ----------------
// Slab layout F[s][n][32] bf16 (s = MFMA k-step), one slab = 3.2MB (L2-size).
// Grid (NCH, 4). Wave = 8 nodes x 8 lanes; lane owns 4 features (uint2, 8B).
// One gather instruction covers 8 nodes x 64B = 512B -> half the instructions
// and 2x the bytes in flight vs the R6 u32 version.
__global__ __launch_bounds__(256) void k_agg_z(const int* __restrict__ offs,
                                               const u32* __restrict__ ep,
                                               const u16* __restrict__ hs,
                                               const u16* __restrict__ x0s,
                                               u16* __restrict__ zs) {
    const int lane = threadIdx.x & 63;
    const int wave = threadIdx.x >> 6;
    const int g  = lane >> 3;          // node group 0..7
    const int f2 = lane & 7;           // uint2 index within 32-feat row
    const int s  = blockIdx.y;
    const int n  = blockIdx.x * 32 + wave * 8 + g;
    const int nc = n < NN ? n : NN - 1;
    const uint2* table = (const uint2*)(hs + (size_t)s * NN * 32);

    const int beg = offs[nc], end = offs[nc + 1];
    float a0 = 0.f, a1 = 0.f, a2 = 0.f, a3 = 0.f;
    int e = beg;
    for (; e + 7 < end; e += 8) {
        u32 r[8]; uint2 v[8];
#pragma unroll
        for (int j = 0; j < 8; ++j) r[j] = ep[e + j];
#pragma unroll
        for (int j = 0; j < 8; ++j)
            v[j] = table[(size_t)(r[j] & 0xffffu) * 8 + f2];
#pragma unroll
        for (int j = 0; j < 8; ++j) {
            float w = bf2f((u16)(r[j] >> 16));
            a0 += w * bf2f((u16)v[j].x);  a1 += w * bf2f((u16)(v[j].x >> 16));
            a2 += w * bf2f((u16)v[j].y);  a3 += w * bf2f((u16)(v[j].y >> 16));
        }
    }
    for (; e < end; ++e) {
        u32 r = ep[e];
        uint2 v = table[(size_t)(r & 0xffffu) * 8 + f2];
        float w = bf2f((u16)(r >> 16));
        a0 += w * bf2f((u16)v.x);  a1 += w * bf2f((u16)(v.x >> 16));
        a2 += w * bf2f((u16)v.y);  a3 += w * bf2f((u16)(v.y >> 16));
    }
    if (n < NN) {
        const size_t idx = (size_t)s * NN * 8 + (size_t)n * 8 + f2;   // uint2 units
        uint2 xv = ((const uint2*)x0s)[idx];
        float z0 = (1.f - ALPHA) * a0 + ALPHA * bf2f((u16)xv.x);
        float z1 = (1.f - ALPHA) * a1 + ALPHA * bf2f((u16)(xv.x >> 16));
        float z2 = (1.f - ALPHA) * a2 + ALPHA * bf2f((u16)xv.y);
        float z3 = (1.f - ALPHA) * a3 + ALPHA * bf2f((u16)(xv.y >> 16));
        uint2 o;
        o.x = (u32)f2bf(z0) | ((u32)f2bf(z1) << 16);
        o.y = (u32)f2bf(z2) | ((u32)f2bf(z3) << 16);
        ((uint2*)zs)[idx] = o;
    }
}

// ---------------- MFMA GEMM (slab-layout node features; verified R5/R6) -----
// MODE 0: Av = x fp32 row-major [M,128]; C = relu(x@W + bias) -> bf16 slab
// MODE 1: Av = z bf16 slab; C = relu(z @ Wfold) -> bf16 slab (no bias)
// MODE 2: Av = h bf16 slab; C = h@W1 + bias -> fp32 row-major [M,64]
template <int MODE>
__global__ __launch_bounds__(256) void k_gemm_mfma(const void* __restrict__ Av,
                                                   const u16* __restrict__ Wt,
                                                   const float* __restrict__ bias,
                                                   void* __restrict__ Cv, int M) {
    constexpr int NT = (MODE == 2) ? 4 : 8;
    const int lane = threadIdx.x & 63;
    const int wave = threadIdx.x >> 6;
    const int q = lane >> 4;
    const int m16 = lane & 15;
    const int node = blockIdx.x * 64 + wave * 16 + m16;
    const int nload = node < M ? node : M - 1;

    short8 zf[4];
    if (MODE == 0) {
        const float* xp = (const float*)Av + (size_t)nload * 128 + q * 8;
#pragma unroll
        for (int s = 0; s < 4; ++s) {
            float4 u0 = *(const float4*)(xp + s * 32);
            float4 u1 = *(const float4*)(xp + s * 32 + 4);
            short8 z;
            z[0] = (short)f2bf(u0.x); z[1] = (short)f2bf(u0.y);
            z[2] = (short)f2bf(u0.z); z[3] = (short)f2bf(u0.w);
            z[4] = (short)f2bf(u1.x); z[5] = (short)f2bf(u1.y);
            z[6] = (short)f2bf(u1.z); z[7] = (short)f2bf(u1.w);
            zf[s] = z;
        }
    } else {
        const u16* ap = (const u16*)Av;
#pragma unroll
        for (int s = 0; s < 4; ++s)
            zf[s] = *(const short8*)(ap + (size_t)s * NN * 32 + (size_t)nload * 32 + q * 8);
    }

    f32x4 acc[NT];
#pragma unroll
    for (int c = 0; c < NT; ++c) {
        f32x4 a = {0.f, 0.f, 0.f, 0.f};
        const u16* wp = Wt + (size_t)(c * 16 + m16) * 128 + q * 8;
#pragma unroll
        for (int s = 0; s < 4; ++s) {
            short8 wf = *(const short8*)(wp + s * 32);
            a = __builtin_amdgcn_mfma_f32_16x16x32_bf16(wf, zf[s], a, 0, 0, 0);
        }
        acc[c] = a;
    }

    if (node < M) {
#pragma unroll
        for (int c = 0; c < NT; ++c) {
            const int f0 = c * 16 + q * 4;
            if (MODE == 2) {
                float4 bv = *(const float4*)(bias + f0);
                float4 o;
                o.x = acc[c][0] + bv.x; o.y = acc[c][1] + bv.y;
                o.z = acc[c][2] + bv.z; o.w = acc[c][3] + bv.w;
                *(float4*)((float*)Cv + (size_t)node * 64 + f0) = o;
            } else {
                float v0 = acc[c][0], v1 = acc[c][1], v2 = acc[c][2], v3 = acc[c][3];
                if (MODE == 0) {
                    float4 bv = *(const float4*)(bias + f0);
                    v0 += bv.x; v1 += bv.y; v2 += bv.z; v3 += bv.w;
                }
                v0 = v0 > 0.f ? v0 : 0.f;
                v1 = v1 > 0.f ? v1 : 0.f;
                v2 = v2 > 0.f ? v2 : 0.f;
                v3 = v3 > 0.f ? v3 : 0.f;
                ushort4 o;
                o.x = f2bf(v0); o.y = f2bf(v1); o.z = f2bf(v2); o.w = f2bf(v3);
                *(ushort4*)((u16*)Cv + (size_t)(f0 >> 5) * NN * 32
                            + (size_t)node * 32 + (f0 & 31)) = o;
            }
        }
    }
}

// ---------------------------------------------------------------------------

extern "C" void kernel_launch(void* const* d_in, const int* in_sizes, int n_in,
                              void* d_out, int out_size, void* d_ws, size_t ws_size,
                              hipStream_t stream) {
    const float* x    = (const float*)d_in[0];
    const int*   esrc = (const int*)d_in[1];
    const int*   edst = (const int*)d_in[2];
    const float* ew   = (const float*)d_in[3];
    const float* W0   = (const float*)d_in[4];
    const float* b0   = (const float*)d_in[5];
    const float* W1   = (const float*)d_in[6];
    const float* b1   = (const float*)d_in[7];
    const float* cw   = (const float*)d_in[8];
    float* out = (float*)d_out;

    const int N = NN, E = EE;

    // workspace layout (all rewritten every call); slab buffers are [4][N][32]
    u32*  ep4   = (u32*)d_ws;                       // E     4B edge records
    u16*  x0s   = (u16*)(ep4 + E);                  // 4*N*32 bf16 x0 (slab)
    u16*  hb1   = x0s + (size_t)4 * N * 32;         // 4*N*32 bf16 h ping
    u16*  hb2   = hb1 + (size_t)4 * N * 32;         // 4*N*32 bf16 h pong
    u16*  zsb   = hb2 + (size_t)4 * N * 32;         // 4*N*32 bf16 z
    u16*  w0t   = zsb + (size_t)4 * N * 32;         // 128*128
    u16*  wft   = w0t + 128 * 128;                  // 6*128*128
    u16*  w1t   = wft + 6 * 128 * 128;              // 64*128
    int*  deg   = (int*)(w1t + 64 * 128);           // N   \  zeroed by one
    int*  bsum  = deg  + N;                         // NB  /  memsetAsync
    int*  offs  = bsum + NB;                        // N+1
    int*  cur   = offs + N + 1;                     // N

    // ---- CSR build + weight prep
    hipMemsetAsync(deg, 0, (size_t)(N + NB) * sizeof(int), stream);
    k_hist_prep<<<HB + PB, 256, 0, stream>>>(edst, deg, W0, cw, W1, w0t, wft, w1t, E);
    k_scan_lb<<<NB, 256, 0, stream>>>(deg, bsum, offs, cur);
    k_bucket_x<<<HB * 8, 256, 0, stream>>>(esrc, edst, ew, cur, ep4, E);

    const int gx = (N + 63) / 64;          // 782 GEMM blocks
    const dim3 ga(NCH, 4);                 // 1563 x 4 aggregate blocks

    // ---- layer 0: x0 = relu(x@W0 + b0)  (fp32 row-major -> bf16 slab)
    k_gemm_mfma<0><<<gx, 256, 0, stream>>>(x, w0t, b0, x0s, N);

    // ---- 6 GCN2 convs: z = 0.9*agg(h) + 0.1*x0 ; h' = relu(z @ Wfold)
    const u16* hin = x0s;
    u16* houts[6] = {hb1, hb2, hb1, hb2, hb1, hb2};
    for (int i = 0; i < 6; ++i) {
        k_agg_z<<<ga, 256, 0, stream>>>(offs, ep4, hin, x0s, zsb);
        k_gemm_mfma<1><<<gx, 256, 0, stream>>>(zsb, wft + (size_t)i * 16384,
                                               nullptr, houts[i], N);
        hin = houts[i];
    }

    // ---- final: out = h@W1 + b1  (bf16 slab -> fp32 row-major)
    k_gemm_mfma<2><<<gx, 256, 0, stream>>>(hb2, w1t, b1, out, N);
}

// Round 9
// 546.024 us; speedup vs baseline: 1.1468x; 1.0116x over previous
//
#include <hip/hip_runtime.h>
#include <cstdint>
#include <cstddef>

// ---------------------------------------------------------------------------
// GCN2: h = relu(x@W0+b0); 6x { agg = scatter_sum(w*h[src] -> dst);
//        z = 0.9*agg + 0.1*x0; h = relu(z @ ((1-b)I + b*Wc)) };
//        out = h@W1 + b1
// R0 871 fp32. R1 770 scan. R2 652 bf16. R3 592 MFMA+fold. R4 626 fusion
// regression. R5/R6 602 slab layout. R7 coop-launch FAILED (harness).
// R8 552: dst-sliced bucket, lookback scan, uint2 agg lanes. Top-5 now
// harness poison fills (~43us fixed floor).
// R9 (this): (a) agg lanes own uint4 (16B): 16 nodes/wave, 1KB/gather-instr,
// 1/4 the issue slots, slab L2 residency kept, grid (782,4)=12512 waves;
// (b) last conv GEMM fused with final h@W1+b1 via padded LDS tile (one less
// dispatch + 25.6MB h round-trip).
// ---------------------------------------------------------------------------

#define NN 50000
#define EE 800000

constexpr float ALPHA   = 0.1f;
constexpr float BETA_C  = 0.05406722127027574f;   // log(0.5/9 + 1)

constexpr int NB = (NN + 255) / 256;              // 196 scan blocks
constexpr int HB = (EE + 255) / 256;              // 3125 edge chunks
constexpr int PREP_TOT = 128 * 128 + 6 * 128 * 128 + 64 * 128;   // 122880
constexpr int PB = (PREP_TOT + 255) / 256;        // 480 prep blocks
constexpr int SLICE = NN / 8;                     // 6250 dst nodes per slice
constexpr int GA = (NN + 63) / 64;                // 782 agg/gemm blocks

typedef unsigned short u16;
typedef unsigned int   u32;
typedef __attribute__((ext_vector_type(8))) short short8;   // 8 bf16 (MFMA A/B)
typedef __attribute__((ext_vector_type(4))) float f32x4;    // MFMA C/D

__device__ __forceinline__ float bf2f(u16 u) {
    union { float f; u32 i; } c; c.i = ((u32)u) << 16; return c.f;
}
__device__ __forceinline__ u16 f2bf(float f) {          // round-to-nearest-even
    union { float f; u32 i; } c; c.f = f;
    u32 r = c.i + 0x7fffu + ((c.i >> 16) & 1u);
    return (u16)(r >> 16);
}

// ------------- merged: histogram (blocks < HB) + weight prep (rest) ---------
__global__ void k_hist_prep(const int* __restrict__ edst, int* __restrict__ deg,
                            const float* __restrict__ W0, const float* __restrict__ cw,
                            const float* __restrict__ W1, u16* __restrict__ w0t,
                            u16* __restrict__ wft, u16* __restrict__ w1t, int E) {
    int b = blockIdx.x;
    if (b < HB) {
        int i = b * 256 + threadIdx.x;
        if (i < E) atomicAdd(&deg[edst[i]], 1);
    } else {
        int i = (b - HB) * 256 + threadIdx.x;
        if (i < 16384) {
            int n = i >> 7, k = i & 127;
            w0t[i] = f2bf(W0[k * 128 + n]);
        } else if (i < 16384 + 6 * 16384) {
            int r = i - 16384;
            int l = r >> 14; int t = r & 16383;
            int n = t >> 7, k = t & 127;
            float v = BETA_C * cw[l * 16384 + k * 128 + n]
                      + ((k == n) ? (1.f - BETA_C) : 0.f);
            wft[r] = f2bf(v);
        } else if (i < PREP_TOT) {
            int r = i - (16384 + 6 * 16384);
            int n = r >> 7, k = r & 127;
            w1t[r] = f2bf(W1[k * 64 + n]);
        }
    }
}

// ---------------- single-dispatch scan: publish-first parallel lookback -----
__global__ __launch_bounds__(256) void k_scan_lb(const int* __restrict__ deg,
                                                 int* __restrict__ bsum,
                                                 int* __restrict__ offs,
                                                 int* __restrict__ cur) {
    __shared__ int sh[256];
    __shared__ int sw[4];
    const int c = blockIdx.x, tid = threadIdx.x;
    const int i = c * 256 + tid;
    int v = (i < NN) ? deg[i] : 0;
    sh[tid] = v;
    __syncthreads();
#pragma unroll
    for (int o = 1; o < 256; o <<= 1) {
        int u = (tid >= o) ? sh[tid - o] : 0;
        __syncthreads();
        sh[tid] += u;
        __syncthreads();
    }
    if (tid == 255) atomicExch(&bsum[c], sh[255] + 1);   // publish (nonzero)
    int part = 0;
    for (int t = tid; t < c; t += 256) {                 // parallel lookback
        int b;
        do { b = atomicAdd(&bsum[t], 0); } while (b == 0);
        part += b - 1;
    }
#pragma unroll
    for (int o = 32; o > 0; o >>= 1) part += __shfl_down(part, o);
    if ((tid & 63) == 0) sw[tid >> 6] = part;
    __syncthreads();
    const int base = sw[0] + sw[1] + sw[2] + sw[3];
    const int ex = base + sh[tid] - v;
    if (i < NN) {
        offs[i] = ex;
        cur[i]  = ex;
        if (i == NN - 1) offs[NN] = ex + v;
    }
}

// ---------------- 8-way dst-sliced bucket scatter ----------------
__global__ void k_bucket_x(const int* __restrict__ src, const int* __restrict__ dst,
                           const float* __restrict__ w, int* __restrict__ cur,
                           u32* __restrict__ ep, int E) {
    const int slice = blockIdx.x & 7;
    const int i = (blockIdx.x >> 3) * 256 + threadIdx.x;
    if (i >= E) return;
    const int d = dst[i];
    const int lo = slice * SLICE;
    if (d >= lo && d < lo + SLICE) {
        int pos = atomicAdd(&cur[d], 1);
        ep[pos] = ((u32)f2bf(w[i]) << 16) | (u32)src[i];
    }
}

// ---------------- slab-tiled aggregate + z-fold (uint4 lanes) ----------------
// Slab layout F[s][n][32] bf16 (s = MFMA k-step), slab = 3.2MB (L2-resident,
// phase-ordered dispatch keeps one slab hot per XCD at a time).
// Grid (782, 4). Wave = 16 nodes x 4 lanes; lane owns 8 feats (uint4, 16B).
// One gather instruction = 16 nodes x 64B = 1KB in flight.
__global__ __launch_bounds__(256) void k_agg_z(const int* __restrict__ offs,
                                               const u32* __restrict__ ep,
                                               const u16* __restrict__ hs,
                                               const u16* __restrict__ x0s,
                                               u16* __restrict__ zs) {
    const int lane = threadIdx.x & 63;
    const int wave = threadIdx.x >> 6;
    const int g  = lane >> 2;          // node group 0..15
    const int f4 = lane & 3;           // uint4 index within 64B slab row
    const int s  = blockIdx.y;
    const int n  = blockIdx.x * 64 + wave * 16 + g;
    const int nc = n < NN ? n : NN - 1;
    const uint4* table = (const uint4*)(hs + (size_t)s * NN * 32);

    const int beg = offs[nc], end = offs[nc + 1];
    float a0 = 0.f, a1 = 0.f, a2 = 0.f, a3 = 0.f;
    float a4 = 0.f, a5 = 0.f, a6 = 0.f, a7 = 0.f;
    int e = beg;
    for (; e + 7 < end; e += 8) {
        u32 r[8]; uint4 v[8];
#pragma unroll
        for (int j = 0; j < 8; ++j) r[j] = ep[e + j];
#pragma unroll
        for (int j = 0; j < 8; ++j)
            v[j] = table[(size_t)(r[j] & 0xffffu) * 4 + f4];
#pragma unroll
        for (int j = 0; j < 8; ++j) {
            float w = bf2f((u16)(r[j] >> 16));
            a0 += w * bf2f((u16)v[j].x);  a1 += w * bf2f((u16)(v[j].x >> 16));
            a2 += w * bf2f((u16)v[j].y);  a3 += w * bf2f((u16)(v[j].y >> 16));
            a4 += w * bf2f((u16)v[j].z);  a5 += w * bf2f((u16)(v[j].z >> 16));
            a6 += w * bf2f((u16)v[j].w);  a7 += w * bf2f((u16)(v[j].w >> 16));
        }
    }
    for (; e < end; ++e) {
        u32 r = ep[e];
        uint4 v = table[(size_t)(r & 0xffffu) * 4 + f4];
        float w = bf2f((u16)(r >> 16));
        a0 += w * bf2f((u16)v.x);  a1 += w * bf2f((u16)(v.x >> 16));
        a2 += w * bf2f((u16)v.y);  a3 += w * bf2f((u16)(v.y >> 16));
        a4 += w * bf2f((u16)v.z);  a5 += w * bf2f((u16)(v.z >> 16));
        a6 += w * bf2f((u16)v.w);  a7 += w * bf2f((u16)(v.w >> 16));
    }
    if (n < NN) {
        const size_t idx = (size_t)s * NN * 4 + (size_t)n * 4 + f4;   // uint4 units
        uint4 xv = ((const uint4*)x0s)[idx];
        float z0 = (1.f - ALPHA) * a0 + ALPHA * bf2f((u16)xv.x);
        float z1 = (1.f - ALPHA) * a1 + ALPHA * bf2f((u16)(xv.x >> 16));
        float z2 = (1.f - ALPHA) * a2 + ALPHA * bf2f((u16)xv.y);
        float z3 = (1.f - ALPHA) * a3 + ALPHA * bf2f((u16)(xv.y >> 16));
        float z4 = (1.f - ALPHA) * a4 + ALPHA * bf2f((u16)xv.z);
        float z5 = (1.f - ALPHA) * a5 + ALPHA * bf2f((u16)(xv.z >> 16));
        float z6 = (1.f - ALPHA) * a6 + ALPHA * bf2f((u16)xv.w);
        float z7 = (1.f - ALPHA) * a7 + ALPHA * bf2f((u16)(xv.w >> 16));
        uint4 o;
        o.x = (u32)f2bf(z0) | ((u32)f2bf(z1) << 16);
        o.y = (u32)f2bf(z2) | ((u32)f2bf(z3) << 16);
        o.z = (u32)f2bf(z4) | ((u32)f2bf(z5) << 16);
        o.w = (u32)f2bf(z6) | ((u32)f2bf(z7) << 16);
        ((uint4*)zs)[idx] = o;
    }
}

// ---------------- MFMA GEMM (slab-layout node features; verified R5-R8) -----
// MODE 0: Av = x fp32 row-major [M,128]; C = relu(x@W + bias) -> bf16 slab
// MODE 1: Av = z bf16 slab; C = relu(z @ Wfold) -> bf16 slab (no bias)
template <int MODE>
__global__ __launch_bounds__(256) void k_gemm_mfma(const void* __restrict__ Av,
                                                   const u16* __restrict__ Wt,
                                                   const float* __restrict__ bias,
                                                   void* __restrict__ Cv, int M) {
    const int lane = threadIdx.x & 63;
    const int wave = threadIdx.x >> 6;
    const int q = lane >> 4;
    const int m16 = lane & 15;
    const int node = blockIdx.x * 64 + wave * 16 + m16;
    const int nload = node < M ? node : M - 1;

    short8 zf[4];
    if (MODE == 0) {
        const float* xp = (const float*)Av + (size_t)nload * 128 + q * 8;
#pragma unroll
        for (int s = 0; s < 4; ++s) {
            float4 u0 = *(const float4*)(xp + s * 32);
            float4 u1 = *(const float4*)(xp + s * 32 + 4);
            short8 z;
            z[0] = (short)f2bf(u0.x); z[1] = (short)f2bf(u0.y);
            z[2] = (short)f2bf(u0.z); z[3] = (short)f2bf(u0.w);
            z[4] = (short)f2bf(u1.x); z[5] = (short)f2bf(u1.y);
            z[6] = (short)f2bf(u1.z); z[7] = (short)f2bf(u1.w);
            zf[s] = z;
        }
    } else {
        const u16* ap = (const u16*)Av;
#pragma unroll
        for (int s = 0; s < 4; ++s)
            zf[s] = *(const short8*)(ap + (size_t)s * NN * 32 + (size_t)nload * 32 + q * 8);
    }

    f32x4 acc[8];
#pragma unroll
    for (int c = 0; c < 8; ++c) {
        f32x4 a = {0.f, 0.f, 0.f, 0.f};
        const u16* wp = Wt + (size_t)(c * 16 + m16) * 128 + q * 8;
#pragma unroll
        for (int s = 0; s < 4; ++s) {
            short8 wf = *(const short8*)(wp + s * 32);
            a = __builtin_amdgcn_mfma_f32_16x16x32_bf16(wf, zf[s], a, 0, 0, 0);
        }
        acc[c] = a;
    }

    if (node < M) {
#pragma unroll
        for (int c = 0; c < 8; ++c) {
            const int f0 = c * 16 + q * 4;
            float v0 = acc[c][0], v1 = acc[c][1], v2 = acc[c][2], v3 = acc[c][3];
            if (MODE == 0) {
                float4 bv = *(const float4*)(bias + f0);
                v0 += bv.x; v1 += bv.y; v2 += bv.z; v3 += bv.w;
            }
            v0 = v0 > 0.f ? v0 : 0.f;
            v1 = v1 > 0.f ? v1 : 0.f;
            v2 = v2 > 0.f ? v2 : 0.f;
            v3 = v3 > 0.f ? v3 : 0.f;
            ushort4 o;
            o.x = f2bf(v0); o.y = f2bf(v1); o.z = f2bf(v2); o.w = f2bf(v3);
            *(ushort4*)((u16*)Cv + (size_t)(f0 >> 5) * NN * 32
                        + (size_t)node * 32 + (f0 & 31)) = o;
        }
    }
}

// ---------------- fused last conv + final projection ----------------
// h = relu(z @ Wfold5) stays on-chip: relu'd h tile -> padded LDS -> re-read
// as B-fragments -> out = h@W1 + b1 (fp32 row-major [N,64]).
__global__ __launch_bounds__(256) void k_gemm_last(const u16* __restrict__ z,
                                                   const u16* __restrict__ wf5,
                                                   const u16* __restrict__ w1t,
                                                   const float* __restrict__ b1,
                                                   float* __restrict__ out) {
    __shared__ __align__(16) u16 hl[4][16][136];   // +8 pad: conflict-free
    const int lane = threadIdx.x & 63;
    const int wave = threadIdx.x >> 6;
    const int q = lane >> 4;
    const int m16 = lane & 15;
    const int node = blockIdx.x * 64 + wave * 16 + m16;
    const int nload = node < NN ? node : NN - 1;

    short8 zf[4];
#pragma unroll
    for (int s = 0; s < 4; ++s)
        zf[s] = *(const short8*)(z + (size_t)s * NN * 32 + (size_t)nload * 32 + q * 8);

    // ---- h = relu(z @ Wfold5), bf16 into LDS
#pragma unroll
    for (int c = 0; c < 8; ++c) {
        f32x4 a = {0.f, 0.f, 0.f, 0.f};
        const u16* wp = wf5 + (size_t)(c * 16 + m16) * 128 + q * 8;
#pragma unroll
        for (int s = 0; s < 4; ++s) {
            short8 wf = *(const short8*)(wp + s * 32);
            a = __builtin_amdgcn_mfma_f32_16x16x32_bf16(wf, zf[s], a, 0, 0, 0);
        }
        float v0 = a[0] > 0.f ? a[0] : 0.f;
        float v1 = a[1] > 0.f ? a[1] : 0.f;
        float v2 = a[2] > 0.f ? a[2] : 0.f;
        float v3 = a[3] > 0.f ? a[3] : 0.f;
        ushort4 o;
        o.x = f2bf(v0); o.y = f2bf(v1); o.z = f2bf(v2); o.w = f2bf(v3);
        *(ushort4*)&hl[wave][m16][c * 16 + q * 4] = o;
    }
    __syncthreads();

    // ---- out = h @ W1 + b1
    short8 hf[4];
#pragma unroll
    for (int s = 0; s < 4; ++s)
        hf[s] = *(const short8*)&hl[wave][m16][s * 32 + q * 8];

    if (node < NN) {
#pragma unroll
        for (int c = 0; c < 4; ++c) {
            f32x4 a = {0.f, 0.f, 0.f, 0.f};
            const u16* wp = w1t + (size_t)(c * 16 + m16) * 128 + q * 8;
#pragma unroll
            for (int s = 0; s < 4; ++s) {
                short8 wf = *(const short8*)(wp + s * 32);
                a = __builtin_amdgcn_mfma_f32_16x16x32_bf16(wf, hf[s], a, 0, 0, 0);
            }
            const int f0 = c * 16 + q * 4;
            float4 bv = *(const float4*)(b1 + f0);
            float4 o;
            o.x = a[0] + bv.x; o.y = a[1] + bv.y;
            o.z = a[2] + bv.z; o.w = a[3] + bv.w;
            *(float4*)(out + (size_t)node * 64 + f0) = o;
        }
    } else {
        // keep MFMA participation uniform across the wave
#pragma unroll
        for (int c = 0; c < 4; ++c) {
            f32x4 a = {0.f, 0.f, 0.f, 0.f};
            const u16* wp = w1t + (size_t)(c * 16 + m16) * 128 + q * 8;
#pragma unroll
            for (int s = 0; s < 4; ++s) {
                short8 wf = *(const short8*)(wp + s * 32);
                a = __builtin_amdgcn_mfma_f32_16x16x32_bf16(wf, hf[s], a, 0, 0, 0);
            }
        }
    }
}

// ---------------------------------------------------------------------------

extern "C" void kernel_launch(void* const* d_in, const int* in_sizes, int n_in,
                              void* d_out, int out_size, void* d_ws, size_t ws_size,
                              hipStream_t stream) {
    const float* x    = (const float*)d_in[0];
    const int*   esrc = (const int*)d_in[1];
    const int*   edst = (const int*)d_in[2];
    const float* ew   = (const float*)d_in[3];
    const float* W0   = (const float*)d_in[4];
    const float* b0   = (const float*)d_in[5];
    const float* W1   = (const float*)d_in[6];
    const float* b1   = (const float*)d_in[7];
    const float* cw   = (const float*)d_in[8];
    float* out = (float*)d_out;

    const int N = NN, E = EE;

    // workspace layout (all rewritten every call); slab buffers are [4][N][32]
    u32*  ep4   = (u32*)d_ws;                       // E     4B edge records
    u16*  x0s   = (u16*)(ep4 + E);                  // 4*N*32 bf16 x0 (slab)
    u16*  hb1   = x0s + (size_t)4 * N * 32;         // 4*N*32 bf16 h ping
    u16*  hb2   = hb1 + (size_t)4 * N * 32;         // 4*N*32 bf16 h pong
    u16*  zsb   = hb2 + (size_t)4 * N * 32;         // 4*N*32 bf16 z
    u16*  w0t   = zsb + (size_t)4 * N * 32;         // 128*128
    u16*  wft   = w0t + 128 * 128;                  // 6*128*128
    u16*  w1t   = wft + 6 * 128 * 128;              // 64*128
    int*  deg   = (int*)(w1t + 64 * 128);           // N   \  zeroed by one
    int*  bsum  = deg  + N;                         // NB  /  memsetAsync
    int*  offs  = bsum + NB;                        // N+1
    int*  cur   = offs + N + 1;                     // N

    // ---- CSR build + weight prep
    hipMemsetAsync(deg, 0, (size_t)(N + NB) * sizeof(int), stream);
    k_hist_prep<<<HB + PB, 256, 0, stream>>>(edst, deg, W0, cw, W1, w0t, wft, w1t, E);
    k_scan_lb<<<NB, 256, 0, stream>>>(deg, bsum, offs, cur);
    k_bucket_x<<<HB * 8, 256, 0, stream>>>(esrc, edst, ew, cur, ep4, E);

    const dim3 ga(GA, 4);                  // 782 x 4 aggregate blocks

    // ---- layer 0: x0 = relu(x@W0 + b0)  (fp32 row-major -> bf16 slab)
    k_gemm_mfma<0><<<GA, 256, 0, stream>>>(x, w0t, b0, x0s, N);

    // ---- convs 0..4: z = 0.9*agg(h) + 0.1*x0 ; h' = relu(z @ Wfold)
    const u16* hin = x0s;
    u16* houts[5] = {hb1, hb2, hb1, hb2, hb1};
    for (int i = 0; i < 5; ++i) {
        k_agg_z<<<ga, 256, 0, stream>>>(offs, ep4, hin, x0s, zsb);
        k_gemm_mfma<1><<<GA, 256, 0, stream>>>(zsb, wft + (size_t)i * 16384,
                                               nullptr, houts[i], N);
        hin = houts[i];
    }

    // ---- conv 5 fused with final projection
    k_agg_z<<<ga, 256, 0, stream>>>(offs, ep4, hin, x0s, zsb);
    k_gemm_last<<<GA, 256, 0, stream>>>(zsb, wft + (size_t)5 * 16384, w1t, b1, out);
}

// Round 10
// 503.873 us; speedup vs baseline: 1.2427x; 1.0837x over previous
//
#include <hip/hip_runtime.h>
#include <cstdint>
#include <cstddef>

// ---------------------------------------------------------------------------
// GCN2: h = relu(x@W0+b0); 6x { agg = scatter_sum(w*h[src] -> dst);
//        z = 0.9*agg + 0.1*x0; h = relu(z @ ((1-b)I + b*Wc)) };
//        out = h@W1 + b1
// R0 871 fp32. R1 770 scan. R2 652 bf16. R3 592 MFMA+fold. R4 626 fusion
// regression. R5/R6 602 slab layout. R7 coop-launch FAILED. R8 552 (sliced
// bucket, lookback scan). R9 546: uint4 agg lanes — but FETCH=98.7MB/conv
// showed slabs are NOT L2-resident: grid (x,4) interleaves all 4 slabs over
// all 8 XCDs -> 12.8MB footprint per 4MB L2 -> thrash.
// R10 (this): XCD-pinned agg grid. 1D grid 3128 blocks; slab=(bid&7)>>1,
// chunk=(bid>>3)*2+(bid&1). With round-robin bid%8 XCD mapping, XCD pair
// {2s,2s+1} only touches slab s (3.2MB < 4MB L2). Neutral if mapping differs.
// ---------------------------------------------------------------------------

#define NN 50000
#define EE 800000

constexpr float ALPHA   = 0.1f;
constexpr float BETA_C  = 0.05406722127027574f;   // log(0.5/9 + 1)

constexpr int NB = (NN + 255) / 256;              // 196 scan blocks
constexpr int HB = (EE + 255) / 256;              // 3125 edge chunks
constexpr int PREP_TOT = 128 * 128 + 6 * 128 * 128 + 64 * 128;   // 122880
constexpr int PB = (PREP_TOT + 255) / 256;        // 480 prep blocks
constexpr int SLICE = NN / 8;                     // 6250 dst nodes per slice
constexpr int GA = (NN + 63) / 64;                // 782 gemm blocks / slab chunks
constexpr int AGGB = 8 * ((GA + 1) / 2);          // 3128 agg blocks (XCD-pinned)

typedef unsigned short u16;
typedef unsigned int   u32;
typedef __attribute__((ext_vector_type(8))) short short8;   // 8 bf16 (MFMA A/B)
typedef __attribute__((ext_vector_type(4))) float f32x4;    // MFMA C/D

__device__ __forceinline__ float bf2f(u16 u) {
    union { float f; u32 i; } c; c.i = ((u32)u) << 16; return c.f;
}
__device__ __forceinline__ u16 f2bf(float f) {          // round-to-nearest-even
    union { float f; u32 i; } c; c.f = f;
    u32 r = c.i + 0x7fffu + ((c.i >> 16) & 1u);
    return (u16)(r >> 16);
}

// ------------- merged: histogram (blocks < HB) + weight prep (rest) ---------
__global__ void k_hist_prep(const int* __restrict__ edst, int* __restrict__ deg,
                            const float* __restrict__ W0, const float* __restrict__ cw,
                            const float* __restrict__ W1, u16* __restrict__ w0t,
                            u16* __restrict__ wft, u16* __restrict__ w1t, int E) {
    int b = blockIdx.x;
    if (b < HB) {
        int i = b * 256 + threadIdx.x;
        if (i < E) atomicAdd(&deg[edst[i]], 1);
    } else {
        int i = (b - HB) * 256 + threadIdx.x;
        if (i < 16384) {
            int n = i >> 7, k = i & 127;
            w0t[i] = f2bf(W0[k * 128 + n]);
        } else if (i < 16384 + 6 * 16384) {
            int r = i - 16384;
            int l = r >> 14; int t = r & 16383;
            int n = t >> 7, k = t & 127;
            float v = BETA_C * cw[l * 16384 + k * 128 + n]
                      + ((k == n) ? (1.f - BETA_C) : 0.f);
            wft[r] = f2bf(v);
        } else if (i < PREP_TOT) {
            int r = i - (16384 + 6 * 16384);
            int n = r >> 7, k = r & 127;
            w1t[r] = f2bf(W1[k * 64 + n]);
        }
    }
}

// ---------------- single-dispatch scan: publish-first parallel lookback -----
__global__ __launch_bounds__(256) void k_scan_lb(const int* __restrict__ deg,
                                                 int* __restrict__ bsum,
                                                 int* __restrict__ offs,
                                                 int* __restrict__ cur) {
    __shared__ int sh[256];
    __shared__ int sw[4];
    const int c = blockIdx.x, tid = threadIdx.x;
    const int i = c * 256 + tid;
    int v = (i < NN) ? deg[i] : 0;
    sh[tid] = v;
    __syncthreads();
#pragma unroll
    for (int o = 1; o < 256; o <<= 1) {
        int u = (tid >= o) ? sh[tid - o] : 0;
        __syncthreads();
        sh[tid] += u;
        __syncthreads();
    }
    if (tid == 255) atomicExch(&bsum[c], sh[255] + 1);   // publish (nonzero)
    int part = 0;
    for (int t = tid; t < c; t += 256) {                 // parallel lookback
        int b;
        do { b = atomicAdd(&bsum[t], 0); } while (b == 0);
        part += b - 1;
    }
#pragma unroll
    for (int o = 32; o > 0; o >>= 1) part += __shfl_down(part, o);
    if ((tid & 63) == 0) sw[tid >> 6] = part;
    __syncthreads();
    const int base = sw[0] + sw[1] + sw[2] + sw[3];
    const int ex = base + sh[tid] - v;
    if (i < NN) {
        offs[i] = ex;
        cur[i]  = ex;
        if (i == NN - 1) offs[NN] = ex + v;
    }
}

// ---------------- 8-way dst-sliced bucket scatter ----------------
__global__ void k_bucket_x(const int* __restrict__ src, const int* __restrict__ dst,
                           const float* __restrict__ w, int* __restrict__ cur,
                           u32* __restrict__ ep, int E) {
    const int slice = blockIdx.x & 7;
    const int i = (blockIdx.x >> 3) * 256 + threadIdx.x;
    if (i >= E) return;
    const int d = dst[i];
    const int lo = slice * SLICE;
    if (d >= lo && d < lo + SLICE) {
        int pos = atomicAdd(&cur[d], 1);
        ep[pos] = ((u32)f2bf(w[i]) << 16) | (u32)src[i];
    }
}

// ---------------- XCD-pinned slab aggregate + z-fold (uint4 lanes) ----------
// Slab layout F[s][n][32] bf16 (s = MFMA k-step), slab = 3.2MB.
// 1D grid AGGB = 3128. slab = (bid&7)>>1, chunk = (bid>>3)*2+(bid&1) in
// [0,782). With bid%8 -> XCD round-robin, XCD pair {2s,2s+1} touches ONLY
// slab s -> slab resident in that XCD's 4MB L2 for the whole dispatch.
// Wave = 16 nodes x 4 lanes; lane owns 8 feats (uint4, 16B); 1KB/gather-instr.
__global__ __launch_bounds__(256) void k_agg_z(const int* __restrict__ offs,
                                               const u32* __restrict__ ep,
                                               const u16* __restrict__ hs,
                                               const u16* __restrict__ x0s,
                                               u16* __restrict__ zs) {
    const int bid = blockIdx.x;
    const int s     = (bid & 7) >> 1;
    const int chunk = ((bid >> 3) << 1) | (bid & 1);     // 0..781
    const int lane = threadIdx.x & 63;
    const int wave = threadIdx.x >> 6;
    const int g  = lane >> 2;          // node group 0..15
    const int f4 = lane & 3;           // uint4 index within 64B slab row
    const int n  = chunk * 64 + wave * 16 + g;
    const int nc = n < NN ? n : NN - 1;
    const uint4* table = (const uint4*)(hs + (size_t)s * NN * 32);

    const int beg = offs[nc], end = offs[nc + 1];
    float a0 = 0.f, a1 = 0.f, a2 = 0.f, a3 = 0.f;
    float a4 = 0.f, a5 = 0.f, a6 = 0.f, a7 = 0.f;
    int e = beg;
    for (; e + 7 < end; e += 8) {
        u32 r[8]; uint4 v[8];
#pragma unroll
        for (int j = 0; j < 8; ++j) r[j] = ep[e + j];
#pragma unroll
        for (int j = 0; j < 8; ++j)
            v[j] = table[(size_t)(r[j] & 0xffffu) * 4 + f4];
#pragma unroll
        for (int j = 0; j < 8; ++j) {
            float w = bf2f((u16)(r[j] >> 16));
            a0 += w * bf2f((u16)v[j].x);  a1 += w * bf2f((u16)(v[j].x >> 16));
            a2 += w * bf2f((u16)v[j].y);  a3 += w * bf2f((u16)(v[j].y >> 16));
            a4 += w * bf2f((u16)v[j].z);  a5 += w * bf2f((u16)(v[j].z >> 16));
            a6 += w * bf2f((u16)v[j].w);  a7 += w * bf2f((u16)(v[j].w >> 16));
        }
    }
    for (; e < end; ++e) {
        u32 r = ep[e];
        uint4 v = table[(size_t)(r & 0xffffu) * 4 + f4];
        float w = bf2f((u16)(r >> 16));
        a0 += w * bf2f((u16)v.x);  a1 += w * bf2f((u16)(v.x >> 16));
        a2 += w * bf2f((u16)v.y);  a3 += w * bf2f((u16)(v.y >> 16));
        a4 += w * bf2f((u16)v.z);  a5 += w * bf2f((u16)(v.z >> 16));
        a6 += w * bf2f((u16)v.w);  a7 += w * bf2f((u16)(v.w >> 16));
    }
    if (n < NN) {
        const size_t idx = (size_t)s * NN * 4 + (size_t)n * 4 + f4;   // uint4 units
        uint4 xv = ((const uint4*)x0s)[idx];
        float z0 = (1.f - ALPHA) * a0 + ALPHA * bf2f((u16)xv.x);
        float z1 = (1.f - ALPHA) * a1 + ALPHA * bf2f((u16)(xv.x >> 16));
        float z2 = (1.f - ALPHA) * a2 + ALPHA * bf2f((u16)xv.y);
        float z3 = (1.f - ALPHA) * a3 + ALPHA * bf2f((u16)(xv.y >> 16));
        float z4 = (1.f - ALPHA) * a4 + ALPHA * bf2f((u16)xv.z);
        float z5 = (1.f - ALPHA) * a5 + ALPHA * bf2f((u16)(xv.z >> 16));
        float z6 = (1.f - ALPHA) * a6 + ALPHA * bf2f((u16)xv.w);
        float z7 = (1.f - ALPHA) * a7 + ALPHA * bf2f((u16)(xv.w >> 16));
        uint4 o;
        o.x = (u32)f2bf(z0) | ((u32)f2bf(z1) << 16);
        o.y = (u32)f2bf(z2) | ((u32)f2bf(z3) << 16);
        o.z = (u32)f2bf(z4) | ((u32)f2bf(z5) << 16);
        o.w = (u32)f2bf(z6) | ((u32)f2bf(z7) << 16);
        ((uint4*)zs)[idx] = o;
    }
}

// ---------------- MFMA GEMM (slab-layout node features; verified R5-R9) -----
// MODE 0: Av = x fp32 row-major [M,128]; C = relu(x@W + bias) -> bf16 slab
// MODE 1: Av = z bf16 slab; C = relu(z @ Wfold) -> bf16 slab (no bias)
template <int MODE>
__global__ __launch_bounds__(256) void k_gemm_mfma(const void* __restrict__ Av,
                                                   const u16* __restrict__ Wt,
                                                   const float* __restrict__ bias,
                                                   void* __restrict__ Cv, int M) {
    const int lane = threadIdx.x & 63;
    const int wave = threadIdx.x >> 6;
    const int q = lane >> 4;
    const int m16 = lane & 15;
    const int node = blockIdx.x * 64 + wave * 16 + m16;
    const int nload = node < M ? node : M - 1;

    short8 zf[4];
    if (MODE == 0) {
        const float* xp = (const float*)Av + (size_t)nload * 128 + q * 8;
#pragma unroll
        for (int s = 0; s < 4; ++s) {
            float4 u0 = *(const float4*)(xp + s * 32);
            float4 u1 = *(const float4*)(xp + s * 32 + 4);
            short8 z;
            z[0] = (short)f2bf(u0.x); z[1] = (short)f2bf(u0.y);
            z[2] = (short)f2bf(u0.z); z[3] = (short)f2bf(u0.w);
            z[4] = (short)f2bf(u1.x); z[5] = (short)f2bf(u1.y);
            z[6] = (short)f2bf(u1.z); z[7] = (short)f2bf(u1.w);
            zf[s] = z;
        }
    } else {
        const u16* ap = (const u16*)Av;
#pragma unroll
        for (int s = 0; s < 4; ++s)
            zf[s] = *(const short8*)(ap + (size_t)s * NN * 32 + (size_t)nload * 32 + q * 8);
    }

    f32x4 acc[8];
#pragma unroll
    for (int c = 0; c < 8; ++c) {
        f32x4 a = {0.f, 0.f, 0.f, 0.f};
        const u16* wp = Wt + (size_t)(c * 16 + m16) * 128 + q * 8;
#pragma unroll
        for (int s = 0; s < 4; ++s) {
            short8 wf = *(const short8*)(wp + s * 32);
            a = __builtin_amdgcn_mfma_f32_16x16x32_bf16(wf, zf[s], a, 0, 0, 0);
        }
        acc[c] = a;
    }

    if (node < M) {
#pragma unroll
        for (int c = 0; c < 8; ++c) {
            const int f0 = c * 16 + q * 4;
            float v0 = acc[c][0], v1 = acc[c][1], v2 = acc[c][2], v3 = acc[c][3];
            if (MODE == 0) {
                float4 bv = *(const float4*)(bias + f0);
                v0 += bv.x; v1 += bv.y; v2 += bv.z; v3 += bv.w;
            }
            v0 = v0 > 0.f ? v0 : 0.f;
            v1 = v1 > 0.f ? v1 : 0.f;
            v2 = v2 > 0.f ? v2 : 0.f;
            v3 = v3 > 0.f ? v3 : 0.f;
            ushort4 o;
            o.x = f2bf(v0); o.y = f2bf(v1); o.z = f2bf(v2); o.w = f2bf(v3);
            *(ushort4*)((u16*)Cv + (size_t)(f0 >> 5) * NN * 32
                        + (size_t)node * 32 + (f0 & 31)) = o;
        }
    }
}

// ---------------- fused last conv + final projection ----------------
__global__ __launch_bounds__(256) void k_gemm_last(const u16* __restrict__ z,
                                                   const u16* __restrict__ wf5,
                                                   const u16* __restrict__ w1t,
                                                   const float* __restrict__ b1,
                                                   float* __restrict__ out) {
    __shared__ __align__(16) u16 hl[4][16][136];   // +8 pad: conflict-free
    const int lane = threadIdx.x & 63;
    const int wave = threadIdx.x >> 6;
    const int q = lane >> 4;
    const int m16 = lane & 15;
    const int node = blockIdx.x * 64 + wave * 16 + m16;
    const int nload = node < NN ? node : NN - 1;

    short8 zf[4];
#pragma unroll
    for (int s = 0; s < 4; ++s)
        zf[s] = *(const short8*)(z + (size_t)s * NN * 32 + (size_t)nload * 32 + q * 8);

    // ---- h = relu(z @ Wfold5), bf16 into LDS
#pragma unroll
    for (int c = 0; c < 8; ++c) {
        f32x4 a = {0.f, 0.f, 0.f, 0.f};
        const u16* wp = wf5 + (size_t)(c * 16 + m16) * 128 + q * 8;
#pragma unroll
        for (int s = 0; s < 4; ++s) {
            short8 wf = *(const short8*)(wp + s * 32);
            a = __builtin_amdgcn_mfma_f32_16x16x32_bf16(wf, zf[s], a, 0, 0, 0);
        }
        float v0 = a[0] > 0.f ? a[0] : 0.f;
        float v1 = a[1] > 0.f ? a[1] : 0.f;
        float v2 = a[2] > 0.f ? a[2] : 0.f;
        float v3 = a[3] > 0.f ? a[3] : 0.f;
        ushort4 o;
        o.x = f2bf(v0); o.y = f2bf(v1); o.z = f2bf(v2); o.w = f2bf(v3);
        *(ushort4*)&hl[wave][m16][c * 16 + q * 4] = o;
    }
    __syncthreads();

    // ---- out = h @ W1 + b1
    short8 hf[4];
#pragma unroll
    for (int s = 0; s < 4; ++s)
        hf[s] = *(const short8*)&hl[wave][m16][s * 32 + q * 8];

#pragma unroll
    for (int c = 0; c < 4; ++c) {
        f32x4 a = {0.f, 0.f, 0.f, 0.f};
        const u16* wp = w1t + (size_t)(c * 16 + m16) * 128 + q * 8;
#pragma unroll
        for (int s = 0; s < 4; ++s) {
            short8 wf = *(const short8*)(wp + s * 32);
            a = __builtin_amdgcn_mfma_f32_16x16x32_bf16(wf, hf[s], a, 0, 0, 0);
        }
        if (node < NN) {
            const int f0 = c * 16 + q * 4;
            float4 bv = *(const float4*)(b1 + f0);
            float4 o;
            o.x = a[0] + bv.x; o.y = a[1] + bv.y;
            o.z = a[2] + bv.z; o.w = a[3] + bv.w;
            *(float4*)(out + (size_t)node * 64 + f0) = o;
        }
    }
}

// ---------------------------------------------------------------------------

extern "C" void kernel_launch(void* const* d_in, const int* in_sizes, int n_in,
                              void* d_out, int out_size, void* d_ws, size_t ws_size,
                              hipStream_t stream) {
    const float* x    = (const float*)d_in[0];
    const int*   esrc = (const int*)d_in[1];
    const int*   edst = (const int*)d_in[2];
    const float* ew   = (const float*)d_in[3];
    const float* W0   = (const float*)d_in[4];
    const float* b0   = (const float*)d_in[5];
    const float* W1   = (const float*)d_in[6];
    const float* b1   = (const float*)d_in[7];
    const float* cw   = (const float*)d_in[8];
    float* out = (float*)d_out;

    const int N = NN, E = EE;

    // workspace layout (all rewritten every call); slab buffers are [4][N][32]
    u32*  ep4   = (u32*)d_ws;                       // E     4B edge records
    u16*  x0s   = (u16*)(ep4 + E);                  // 4*N*32 bf16 x0 (slab)
    u16*  hb1   = x0s + (size_t)4 * N * 32;         // 4*N*32 bf16 h ping
    u16*  hb2   = hb1 + (size_t)4 * N * 32;         // 4*N*32 bf16 h pong
    u16*  zsb   = hb2 + (size_t)4 * N * 32;         // 4*N*32 bf16 z
    u16*  w0t   = zsb + (size_t)4 * N * 32;         // 128*128
    u16*  wft   = w0t + 128 * 128;                  // 6*128*128
    u16*  w1t   = wft + 6 * 128 * 128;              // 64*128
    int*  deg   = (int*)(w1t + 64 * 128);           // N   \  zeroed by one
    int*  bsum  = deg  + N;                         // NB  /  memsetAsync
    int*  offs  = bsum + NB;                        // N+1
    int*  cur   = offs + N + 1;                     // N

    // ---- CSR build + weight prep
    hipMemsetAsync(deg, 0, (size_t)(N + NB) * sizeof(int), stream);
    k_hist_prep<<<HB + PB, 256, 0, stream>>>(edst, deg, W0, cw, W1, w0t, wft, w1t, E);
    k_scan_lb<<<NB, 256, 0, stream>>>(deg, bsum, offs, cur);
    k_bucket_x<<<HB * 8, 256, 0, stream>>>(esrc, edst, ew, cur, ep4, E);

    // ---- layer 0: x0 = relu(x@W0 + b0)  (fp32 row-major -> bf16 slab)
    k_gemm_mfma<0><<<GA, 256, 0, stream>>>(x, w0t, b0, x0s, N);

    // ---- convs 0..4: z = 0.9*agg(h) + 0.1*x0 ; h' = relu(z @ Wfold)
    const u16* hin = x0s;
    u16* houts[5] = {hb1, hb2, hb1, hb2, hb1};
    for (int i = 0; i < 5; ++i) {
        k_agg_z<<<AGGB, 256, 0, stream>>>(offs, ep4, hin, x0s, zsb);
        k_gemm_mfma<1><<<GA, 256, 0, stream>>>(zsb, wft + (size_t)i * 16384,
                                               nullptr, houts[i], N);
        hin = houts[i];
    }

    // ---- conv 5 fused with final projection
    k_agg_z<<<AGGB, 256, 0, stream>>>(offs, ep4, hin, x0s, zsb);
    k_gemm_last<<<GA, 256, 0, stream>>>(zsb, wft + (size_t)5 * 16384, w1t, b1, out);
}